// Round 3
// baseline (621.248 us; speedup 1.0000x reference)
//
#include <hip/hip_runtime.h>
#include <hip/hip_fp16.h>

#define NB 4096
#define NT 256
#define NC 64
#define NH 16
#define NS 10
#define NTO 255

// split-path workspace layout
#define XWS_BYTES  33554432ull            // NB*16*NT fp16
#define H_BYTES    67108864ull            // NB*NT*16 f32
#define ACT_BYTES  41943040ull            // NB*NT*10 f32
#define WS_NEEDED  (XWS_BYTES + H_BYTES + ACT_BYTES)

__device__ __forceinline__ float fast_rcp(float x){ return __builtin_amdgcn_rcpf(x); }
__device__ __forceinline__ float fast_rsq(float x){ return __builtin_amdgcn_rsqf(x); }
__device__ __forceinline__ float fsig(float x){ return fast_rcp(1.0f + __expf(-x)); }
__device__ __forceinline__ float ftanh(float x){
    float e = __expf(2.0f*x);
    return fmaf(-2.0f, fast_rcp(e + 1.0f), 1.0f);
}

// row_ror:R within each 16-lane row: lane l receives lane (l-R)&15's value. VALU pipe, no LDS.
template<int R>
__device__ __forceinline__ float rotf(float x){
    return __int_as_float(__builtin_amdgcn_update_dpp(
        0, __float_as_int(x), 0x120 + R, 0xF, 0xF, true));
}
__device__ __forceinline__ float row_bcast_sum(float x){
    x += rotf<8>(x);
    x += rotf<4>(x);
    x += rotf<2>(x);
    x += rotf<1>(x);
    return x;
}
// acc + sum_k v_k * W[k][l], v distributed one element/lane, w[r] = W[(l-r)&15][l]
__device__ __forceinline__ float rotdot16(float v, const float* w, float acc){
    float a1 = 0.f;
    acc = fmaf(v,          w[0],  acc);
    a1  = fmaf(rotf<1>(v), w[1],  a1);
    acc = fmaf(rotf<2>(v), w[2],  acc);
    a1  = fmaf(rotf<3>(v), w[3],  a1);
    acc = fmaf(rotf<4>(v), w[4],  acc);
    a1  = fmaf(rotf<5>(v), w[5],  a1);
    acc = fmaf(rotf<6>(v), w[6],  acc);
    a1  = fmaf(rotf<7>(v), w[7],  a1);
    acc = fmaf(rotf<8>(v), w[8],  acc);
    a1  = fmaf(rotf<9>(v), w[9],  a1);
    acc = fmaf(rotf<10>(v),w[10], acc);
    a1  = fmaf(rotf<11>(v),w[11], a1);
    acc = fmaf(rotf<12>(v),w[12], acc);
    a1  = fmaf(rotf<13>(v),w[13], a1);
    acc = fmaf(rotf<14>(v),w[14], acc);
    a1  = fmaf(rotf<15>(v),w[15], a1);
    return acc + a1;
}

// extract half #u (0..7, compile-time after unroll) from a float4 holding 8 fp16
__device__ __forceinline__ float xw_at(float4 v, int u){
    unsigned w = (u<2) ? __float_as_uint(v.x) : (u<4) ? __float_as_uint(v.y)
               : (u<6) ? __float_as_uint(v.z) : __float_as_uint(v.w);
    unsigned hh = (u & 1) ? (w >> 16) : (w & 0xffffu);
    return __half2float(__ushort_as_half((unsigned short)hh));
}

// static component select (c must be compile-time after unroll)
__device__ __forceinline__ float comp4(float4 v, int c){
    return c==0 ? v.x : c==1 ? v.y : c==2 ? v.z : v.w;
}

// ===================== K1: xw = LN(cov) @ (gamma-folded wx) + (beta@wx + rnn_b) =====================
__global__ __launch_bounds__(256, 4) void xw_kernel(
    const float* __restrict__ cov, const float* __restrict__ lng,
    const float* __restrict__ lnb, const float* __restrict__ wx,
    const float* __restrict__ rnb, __half* __restrict__ xws)
{
    const int wid  = threadIdx.x >> 6;
    const int lane = threadIdx.x & 63;
    const int g = lane >> 4, l = lane & 15;
    const int b = (blockIdx.x << 2) + wid;

    float gwr[64];
    #pragma unroll
    for (int r = 0; r < 16; ++r) {
        int c0 = 4 * ((l - r) & 15);
        #pragma unroll
        for (int j = 0; j < 4; ++j)
            gwr[4*r+j] = lng[c0+j] * wx[(c0+j)*NH + l];
    }
    float bwb = rnb[l];
    #pragma unroll
    for (int c = 0; c < NC; ++c) bwb = fmaf(lnb[c], wx[c*NH + l], bwb);

    const float4* gp = (const float4*)cov + (size_t)b*NT*16 + g*16 + l;
    __half* op = xws + ((size_t)b*16 + l)*NT + g;

    float4 cur = gp[0];
    float4 nxt = gp[64];
    #pragma unroll 2
    for (int it = 0; it < 64; ++it) {
        float4 x = cur;
        cur = nxt;
        if (it < 62) nxt = gp[(size_t)(it+2)*64];
        float ss = (x.x + x.y) + (x.z + x.w);
        float sq = fmaf(x.x,x.x, fmaf(x.y,x.y, fmaf(x.z,x.z, x.w*x.w)));
        ss = row_bcast_sum(ss);
        sq = row_bcast_sum(sq);
        float mu  = ss * (1.0f/64.0f);
        float var = fmaf(-mu, mu, sq * (1.0f/64.0f));
        float rs  = fast_rsq(var + 0.001f);
        float nmu = -mu * rs;
        float x0 = fmaf(x.x, rs, nmu), x1 = fmaf(x.y, rs, nmu);
        float x2 = fmaf(x.z, rs, nmu), x3 = fmaf(x.w, rs, nmu);
        float a0 = bwb, a1 = 0.f, a2 = 0.f, a3 = 0.f;
        a0 = fmaf(x0, gwr[0], a0); a1 = fmaf(x1, gwr[1], a1);
        a2 = fmaf(x2, gwr[2], a2); a3 = fmaf(x3, gwr[3], a3);
#define ROTSTEP(R) { float r0=rotf<R>(x0), r1=rotf<R>(x1), r2=rotf<R>(x2), r3=rotf<R>(x3); \
        a0=fmaf(r0,gwr[4*R+0],a0); a1=fmaf(r1,gwr[4*R+1],a1); \
        a2=fmaf(r2,gwr[4*R+2],a2); a3=fmaf(r3,gwr[4*R+3],a3); }
        ROTSTEP(1)  ROTSTEP(2)  ROTSTEP(3)  ROTSTEP(4)  ROTSTEP(5)
        ROTSTEP(6)  ROTSTEP(7)  ROTSTEP(8)  ROTSTEP(9)  ROTSTEP(10)
        ROTSTEP(11) ROTSTEP(12) ROTSTEP(13) ROTSTEP(14) ROTSTEP(15)
#undef ROTSTEP
        float xw = (a0+a1)+(a2+a3);
        op[it*4] = __float2half(xw);
    }
}

// ===================== K2a: RNN scan only (minimal serial work) =====================
// 1024 blocks x 1 wave; lane = g*16+l; 4 batches/wave. Writes h f32 to hbuf[b][t][16].
__global__ __launch_bounds__(64, 1) void rnn_kernel(
    const __half* __restrict__ xws, const float* __restrict__ wh,
    float* __restrict__ hbuf)
{
    const int lane = threadIdx.x;
    const int g = lane >> 4, l = lane & 15;
    const int b = (blockIdx.x << 2) + g;

    float whr[NH];
    #pragma unroll
    for (int r = 0; r < NH; ++r) whr[r] = wh[((l - r) & 15)*NH + l];

    const float4* xp = (const float4*)(xws + ((size_t)b*16 + l)*NT);
    float* hp = hbuf + (size_t)b*NT*16 + l;     // + t*16

    float4 xa = xp[0], xb = xp[1];
    float h = 0.f;
    #pragma unroll 1
    for (int tt = 0; tt < 32; ++tt) {
        float4 xc = xa; xa = xb;
        if (tt < 30) xb = xp[tt+2];
        float* hst = hp + (size_t)tt*128;       // 8 steps * 16
        #pragma unroll
        for (int u = 0; u < 8; ++u) {
            h = ftanh(rotdot16(h, whr, xw_at(xc, u)));
            hst[u*16] = h;
        }
    }
}

// ===================== K2b: driver MLP, parallel over (B,T) =====================
// 1024 blocks x 4 waves = 4096 waves (4/SIMD). Wave = one batch, sweeps t = 4k+g.
// Fully coalesced h reads (64 lanes -> 256 B contiguous). act[item][10] f32.
__global__ __launch_bounds__(256, 4) void mlp_kernel(
    const float* __restrict__ hbuf, const float* __restrict__ d1w,
    const float* __restrict__ d1b,  const float* __restrict__ d2w,
    const float* __restrict__ d2b,  float* __restrict__ act)
{
    const int wid  = threadIdx.x >> 6;
    const int lane = threadIdx.x & 63;
    const int g = lane >> 4, l = lane & 15;
    const int b = (blockIdx.x << 2) + wid;      // one batch per wave

    float d1r[NH], d2r[NH];
    #pragma unroll
    for (int r = 0; r < NH; ++r) {
        int src = (l - r) & 15;
        d1r[r] = d1w[src*NH + l];
        d2r[r] = d2w[src*NH + l];
    }
    const float d1bl = d1b[l], d2bl = d2b[l];
    const float Aa = (l==0)?0.4f:(l==2)?0.5f:(l==3)?0.1f:(l==4)?0.2f:(l==8)?0.35f:(l==9)?0.1f:1.0f;
    const float Ba = (l==0)?2.0f:1.0f;
    const float Ca = (l==0)?-0.2f:0.0f;

    const float* hp = hbuf + ((size_t)b*NT + g)*16 + l;   // + k*64 (t = 4k+g)
    float* ap = act + ((size_t)b*NT + g)*10 + l;          // + k*40

    float hcur = hp[0];
    float hnxt = hp[64];
    #pragma unroll 4
    for (int k = 0; k < 64; ++k) {
        float hv = hcur; hcur = hnxt;
        if (k < 62) hnxt = hp[(k+2)*64];
        float t1 = ftanh(rotdot16(hv, d1r, d1bl));
        float dv = rotdot16(t1, d2r, d2bl);
        float av = fmaf(Aa, fsig(Ba*dv), Ca);
        if (l < NS) ap[k*40] = av;
    }
}

// ===================== K2c: cash-budget scan (thin recurrence) =====================
// 1024 blocks x 1 wave; 4 batches/wave; every lane computes the full budget, selects
// its output element. Drivers streamed in 4-step groups (10 x float4), double-buffered.
__global__ __launch_bounds__(64, 1) void budget_kernel(
    const float* __restrict__ states, const float* __restrict__ act,
    float* __restrict__ out)
{
    const int lane = threadIdx.x;
    const int g = lane >> 4, l = lane & 15;
    const int b = (blockIdx.x << 2) + g;

    float s0,s1,s2,s3,s4,s5,s6,s7,s8,s9;
    { const float* sp = states + (size_t)b*NT*NS;
      s0=sp[0];s1=sp[1];s2=sp[2];s3=sp[3];s4=sp[4];
      s5=sp[5];s6=sp[6];s7=sp[7];s8=sp[8];s9=sp[9]; }

    float* spo = out + (size_t)b*NTO*NS + l;
    float* ipo = out + (size_t)NB*NTO*NS + (size_t)b*NTO*7 + l;

    const float4* gp4 = (const float4*)(act + (size_t)b*NT*10);  // 10 float4 per 4-step group

    float4 ca[10], cb[10];

#define DD(BUF,J,I) comp4(BUF[((J)*10+(I))>>2], ((J)*10+(I))&3)

#define BSTEP(BUF,J) do { \
    float d0=DD(BUF,J,0), d1=DD(BUF,J,1), d2=DD(BUF,J,2), d3=DD(BUF,J,3), d4=DD(BUF,J,4); \
    float d5=DD(BUF,J,5), d6=DD(BUF,J,6), d7=DD(BUF,J,7), d8=DD(BUF,J,8), d9=DD(BUF,J,9); \
    float rev   = fmaf(s0, d0, s0); \
    float cogs  = d1 * rev; \
    float opex  = d2 * rev; \
    float dep   = d3 * s4; \
    float inte  = d9 * s6; \
    float ebt   = (((rev - cogs) - opex) - dep) - inte; \
    float tax   = d8 * fmaxf(ebt, 0.0f); \
    float ni    = ebt - tax; \
    float arn   = d5 * rev; \
    float invn  = d6 * cogs; \
    float apn   = d7 * cogs; \
    float capex = d4 * rev; \
    float ppen  = (s4 + capex) - dep; \
    float cashn = (((((s1 + ni) + dep) - capex) - (arn - s2)) - (invn - s3)) + (apn - s5); \
    float ren   = s8 + ni; \
    s0=rev; s1=cashn; s2=arn; s3=invn; s4=ppen; s5=apn; s8=ren; \
    float sv = (l==0)?rev:(l==1)?cashn:(l==2)?arn:(l==3)?invn:(l==4)?ppen: \
               (l==5)?apn:(l==6)?s6:(l==7)?s7:(l==8)?ren:s9; \
    float iv = (l==0)?rev:(l==1)?cogs:(l==2)?opex:(l==3)?dep:(l==4)?inte:(l==5)?tax:ni; \
    if (l < NS) *spo = sv; \
    if (l < 7)  *ipo = iv; \
    spo += NS; ipo += 7; \
} while(0)

#define LOADG(BUF, K) { _Pragma("unroll") \
    for (int q = 0; q < 10; ++q) BUF[q] = gp4[(size_t)(K)*10 + q]; }

    // prologue: group 0 (t=1..3; t=0 skipped) and group 1 prefetched
    LOADG(ca, 0)
    LOADG(cb, 1)
    BSTEP(ca,1); BSTEP(ca,2); BSTEP(ca,3);
    LOADG(ca, 2)

    // main: pairs (1,2),(3,4),...,(61,62)
    #pragma unroll 1
    for (int k = 1; k <= 61; k += 2) {
        BSTEP(cb,0); BSTEP(cb,1); BSTEP(cb,2); BSTEP(cb,3);   // group k
        LOADG(cb, k+2)
        BSTEP(ca,0); BSTEP(ca,1); BSTEP(ca,2); BSTEP(ca,3);   // group k+1
        if (k+3 < 64) LOADG(ca, k+3)
    }
    // epilogue: group 63
    BSTEP(cb,0); BSTEP(cb,1); BSTEP(cb,2); BSTEP(cb,3);

#undef LOADG
#undef BSTEP
#undef DD
}

// ===================== fallback: proven monolithic scan (round-0, 180 us) =====================
__global__ __launch_bounds__(64, 1) void scan_fallback(
    const float* __restrict__ states, const __half* __restrict__ xws,
    const float* __restrict__ wh,     const float* __restrict__ d1w,
    const float* __restrict__ d1b,    const float* __restrict__ d2w,
    const float* __restrict__ d2b,    float* __restrict__ out)
{
    const int lane = threadIdx.x;
    const int g = lane >> 4, l = lane & 15;
    const int b = (blockIdx.x << 2) + g;

    __shared__ __align__(16) float db[64];

    float whr[NH], d1r[NH], d2r[NH];
    #pragma unroll
    for (int r = 0; r < NH; ++r) {
        int src = (l - r) & 15;
        whr[r] = wh[src*NH + l];
        d1r[r] = d1w[src*NH + l];
        d2r[r] = d2w[src*NH + l];
    }
    const float d1bl = d1b[l], d2bl = d2b[l];
    const float Aa = (l==0)?0.4f:(l==2)?0.5f:(l==3)?0.1f:(l==4)?0.2f:(l==8)?0.35f:(l==9)?0.1f:1.0f;
    const float Ba = (l==0)?2.0f:1.0f;
    const float Ca = (l==0)?-0.2f:0.0f;

    float s0,s1,s2,s3,s4,s5,s6,s7,s8,s9;
    { const float* sp = states + (size_t)b*NT*NS;
      s0=sp[0];s1=sp[1];s2=sp[2];s3=sp[3];s4=sp[4];
      s5=sp[5];s6=sp[6];s7=sp[7];s8=sp[8];s9=sp[9]; }

    float* spo = out + (size_t)b*NTO*NS + l;
    float* ipo = out + (size_t)NB*NTO*NS + (size_t)b*NTO*7 + l;

    const ushort4* xp = (const ushort4*)(xws + ((size_t)b*16 + l)*NT);
    ushort4 xa = xp[0], xb = xp[1];

    float h = 0.f;
    #pragma unroll 1
    for (int tt = 0; tt < 64; ++tt) {
        ushort4 xc = xa; xa = xb;
        if (tt < 62) xb = xp[tt+2];
        #pragma unroll
        for (int u = 0; u < 4; ++u) {
            const int t = tt*4 + u;
            float xwv = __half2float(__ushort_as_half(u==0?xc.x:u==1?xc.y:u==2?xc.z:xc.w));
            h = ftanh(rotdot16(h, whr, xwv));
            if (t > 0) {
                float t1  = ftanh(rotdot16(h, d1r, d1bl));
                float dv  = rotdot16(t1, d2r, d2bl);
                float act = fmaf(Aa, fsig(Ba * dv), Ca);
                db[lane] = act;
                float4 w0 = *((const float4*)db + g*4);
                float4 w1 = *((const float4*)db + g*4 + 1);
                float2 w2 = *((const float2*)(db + g*16 + 8));

                float rev   = fmaf(s0, w0.x, s0);
                float cogs  = w0.y * rev;
                float opex  = w0.z * rev;
                float dep   = w0.w * s4;
                float inte  = w2.y * s6;
                float ebt   = (((rev - cogs) - opex) - dep) - inte;
                float tax   = w2.x * fmaxf(ebt, 0.0f);
                float ni    = ebt - tax;
                float arn   = w1.y * rev;
                float invn  = w1.z * cogs;
                float apn   = w1.w * cogs;
                float capex = w1.x * rev;
                float ppen  = (s4 + capex) - dep;
                float cashn = (((((s1 + ni) + dep) - capex) - (arn - s2)) - (invn - s3)) + (apn - s5);
                float ren   = s8 + ni;

                s0=rev; s1=cashn; s2=arn; s3=invn; s4=ppen; s5=apn; s8=ren;

                float sv = (l==0)?rev:(l==1)?cashn:(l==2)?arn:(l==3)?invn:(l==4)?ppen:
                           (l==5)?apn:(l==6)?s6:(l==7)?s7:(l==8)?ren:s9;
                float iv = (l==0)?rev:(l==1)?cogs:(l==2)?opex:(l==3)?dep:(l==4)?inte:(l==5)?tax:ni;
                if (l < NS) *spo = sv;
                if (l < 7)  *ipo = iv;
                spo += NS; ipo += 7;
            }
        }
    }
}

extern "C" void kernel_launch(void* const* d_in, const int* in_sizes, int n_in,
                              void* d_out, int out_size, void* d_ws, size_t ws_size,
                              hipStream_t stream) {
    (void)in_sizes; (void)n_in; (void)out_size;
    __half* xws = (__half*)d_ws;
    xw_kernel<<<NB/4, 256, 0, stream>>>(
        (const float*)d_in[1],  // covariates_seq
        (const float*)d_in[2],  // ln_gamma
        (const float*)d_in[3],  // ln_beta
        (const float*)d_in[4],  // rnn_wx
        (const float*)d_in[6],  // rnn_b
        xws);
    if (ws_size >= WS_NEEDED) {
        float* hbuf = (float*)((char*)d_ws + XWS_BYTES);
        float* actb = (float*)((char*)d_ws + XWS_BYTES + H_BYTES);
        rnn_kernel<<<NB/4, 64, 0, stream>>>(
            xws, (const float*)d_in[5], hbuf);
        mlp_kernel<<<NB/4, 256, 0, stream>>>(
            hbuf,
            (const float*)d_in[7],  // d1_w
            (const float*)d_in[8],  // d1_b
            (const float*)d_in[9],  // d2_w
            (const float*)d_in[10], // d2_b
            actb);
        budget_kernel<<<NB/4, 64, 0, stream>>>(
            (const float*)d_in[0], actb, (float*)d_out);
    } else {
        scan_fallback<<<NB/4, 64, 0, stream>>>(
            (const float*)d_in[0],  // states_seq
            xws,
            (const float*)d_in[5],  // rnn_wh
            (const float*)d_in[7],  // d1_w
            (const float*)d_in[8],  // d1_b
            (const float*)d_in[9],  // d2_w
            (const float*)d_in[10], // d2_b
            (float*)d_out);
    }
}

// Round 5
// 589.006 us; speedup vs baseline: 1.0547x; 1.0547x over previous
//
#include <hip/hip_runtime.h>
#include <hip/hip_fp16.h>

#define NB 4096
#define NT 256
#define NC 64
#define NH 16
#define NS 10
#define NTO 255

__device__ __forceinline__ float fast_rcp(float x){ return __builtin_amdgcn_rcpf(x); }
__device__ __forceinline__ float fast_rsq(float x){ return __builtin_amdgcn_rsqf(x); }
__device__ __forceinline__ float fsig(float x){ return fast_rcp(1.0f + __expf(-x)); }
__device__ __forceinline__ float ftanh(float x){
    float e = __expf(2.0f*x);
    return fmaf(-2.0f, fast_rcp(e + 1.0f), 1.0f);
}

// row_ror:R within each 16-lane row: lane l receives lane (l-R)&15's value. VALU pipe, no LDS.
template<int R>
__device__ __forceinline__ float rotf(float x){
    return __int_as_float(__builtin_amdgcn_update_dpp(
        0, __float_as_int(x), 0x120 + R, 0xF, 0xF, true));
}
// butterfly sum over the 16-lane row, result broadcast to all 16 lanes
__device__ __forceinline__ float row_bcast_sum(float x){
    x += rotf<8>(x);
    x += rotf<4>(x);
    x += rotf<2>(x);
    x += rotf<1>(x);
    return x;
}
// acc + sum_k v_k * W[k][l]; 4 accumulation chains of 4 FMAs -> dep chain ~32cy
// (rot latency + 4 fma + 2 merge adds) vs 44cy for the 2-chain version.
__device__ __forceinline__ float rotdot16_4(float v, const float* w, float acc){
    float a1 = 0.f, a2 = 0.f, a3 = 0.f;
    acc = fmaf(v,           w[0],  acc);
    a1  = fmaf(rotf<1>(v),  w[1],  a1);
    a2  = fmaf(rotf<2>(v),  w[2],  a2);
    a3  = fmaf(rotf<3>(v),  w[3],  a3);
    acc = fmaf(rotf<4>(v),  w[4],  acc);
    a1  = fmaf(rotf<5>(v),  w[5],  a1);
    a2  = fmaf(rotf<6>(v),  w[6],  a2);
    a3  = fmaf(rotf<7>(v),  w[7],  a3);
    acc = fmaf(rotf<8>(v),  w[8],  acc);
    a1  = fmaf(rotf<9>(v),  w[9],  a1);
    a2  = fmaf(rotf<10>(v), w[10], a2);
    a3  = fmaf(rotf<11>(v), w[11], a3);
    acc = fmaf(rotf<12>(v), w[12], acc);
    a1  = fmaf(rotf<13>(v), w[13], a1);
    a2  = fmaf(rotf<14>(v), w[14], a2);
    a3  = fmaf(rotf<15>(v), w[15], a3);
    return (acc + a1) + (a2 + a3);
}

// ===================== K1: xw = LN(cov) @ (gamma-folded wx) + (beta@wx + rnn_b) =====================
// One wave per batch (4096 waves, 16/CU). Lane = g*16+l: g = t-subindex (4 t/iter), l = element-quarter.
__global__ __launch_bounds__(256, 4) void xw_kernel(
    const float* __restrict__ cov, const float* __restrict__ lng,
    const float* __restrict__ lnb, const float* __restrict__ wx,
    const float* __restrict__ rnb, __half* __restrict__ xws)
{
    const int wid  = threadIdx.x >> 6;
    const int lane = threadIdx.x & 63;
    const int g = lane >> 4, l = lane & 15;
    const int b = (blockIdx.x << 2) + wid;

    float gwr[64];
    #pragma unroll
    for (int r = 0; r < 16; ++r) {
        int c0 = 4 * ((l - r) & 15);
        #pragma unroll
        for (int j = 0; j < 4; ++j)
            gwr[4*r+j] = lng[c0+j] * wx[(c0+j)*NH + l];
    }
    float bwb = rnb[l];
    #pragma unroll
    for (int c = 0; c < NC; ++c) bwb = fmaf(lnb[c], wx[c*NH + l], bwb);

    const float4* gp = (const float4*)cov + (size_t)b*NT*16 + g*16 + l;
    __half* op = xws + ((size_t)b*16 + l)*NT + g;

    float4 cur = gp[0];
    float4 nxt = gp[64];
    #pragma unroll 2
    for (int it = 0; it < 64; ++it) {
        float4 x = cur;
        cur = nxt;
        if (it < 62) nxt = gp[(size_t)(it+2)*64];
        float ss = (x.x + x.y) + (x.z + x.w);
        float sq = fmaf(x.x,x.x, fmaf(x.y,x.y, fmaf(x.z,x.z, x.w*x.w)));
        ss = row_bcast_sum(ss);
        sq = row_bcast_sum(sq);
        float mu  = ss * (1.0f/64.0f);
        float var = fmaf(-mu, mu, sq * (1.0f/64.0f));
        float rs  = fast_rsq(var + 0.001f);
        float nmu = -mu * rs;
        float x0 = fmaf(x.x, rs, nmu), x1 = fmaf(x.y, rs, nmu);
        float x2 = fmaf(x.z, rs, nmu), x3 = fmaf(x.w, rs, nmu);
        float a0 = bwb, a1 = 0.f, a2 = 0.f, a3 = 0.f;
        a0 = fmaf(x0, gwr[0], a0); a1 = fmaf(x1, gwr[1], a1);
        a2 = fmaf(x2, gwr[2], a2); a3 = fmaf(x3, gwr[3], a3);
#define ROTSTEP(R) { float r0=rotf<R>(x0), r1=rotf<R>(x1), r2=rotf<R>(x2), r3=rotf<R>(x3); \
        a0=fmaf(r0,gwr[4*R+0],a0); a1=fmaf(r1,gwr[4*R+1],a1); \
        a2=fmaf(r2,gwr[4*R+2],a2); a3=fmaf(r3,gwr[4*R+3],a3); }
        ROTSTEP(1)  ROTSTEP(2)  ROTSTEP(3)  ROTSTEP(4)  ROTSTEP(5)
        ROTSTEP(6)  ROTSTEP(7)  ROTSTEP(8)  ROTSTEP(9)  ROTSTEP(10)
        ROTSTEP(11) ROTSTEP(12) ROTSTEP(13) ROTSTEP(14) ROTSTEP(15)
#undef ROTSTEP
        float xw = (a0+a1)+(a2+a3);
        op[it*4] = __float2half(xw);
    }
}

// ===================== K2: fused scan, budget deferred one step =====================
// 1024 blocks x 1 wave; lane = g*16+l, g = batch-in-wave, l = hidden index.
// Per step t: [ds_read act(t-1)] [RNN(t): serial chain] [budget(t-1): independent,
// fills RNN stall slots; LDS latency hidden under RNN chain] [MLP(t) -> ds_write].
// 8-slot rotating LDS act buffer: write slot t&7, read slot (t-1)&7; single wave,
// in-order LDS pipe -> no barriers (same guarantee as the proven baseline).
__global__ __launch_bounds__(64, 1) void scan_kernel(
    const float* __restrict__ states, const __half* __restrict__ xws,
    const float* __restrict__ wh,     const float* __restrict__ d1w,
    const float* __restrict__ d1b,    const float* __restrict__ d2w,
    const float* __restrict__ d2b,    float* __restrict__ out)
{
    const int lane = threadIdx.x;
    const int g = lane >> 4, l = lane & 15;
    const int b = (blockIdx.x << 2) + g;

    __shared__ __align__(16) float db[8*64];   // 8-slot rotating act broadcast, 2 KB

    float whr[NH], d1r[NH], d2r[NH];
    #pragma unroll
    for (int r = 0; r < NH; ++r) {
        int src = (l - r) & 15;
        whr[r] = wh[src*NH + l];
        d1r[r] = d1w[src*NH + l];
        d2r[r] = d2w[src*NH + l];
    }
    const float d1bl = d1b[l], d2bl = d2b[l];
    // per-lane driver activation: act = A*sigmoid(B*x) + C  (lane0: 0.2*tanh via sig)
    const float Aa = (l==0)?0.4f:(l==2)?0.5f:(l==3)?0.1f:(l==4)?0.2f:(l==8)?0.35f:(l==9)?0.1f:1.0f;
    const float Ba = (l==0)?2.0f:1.0f;
    const float Ca = (l==0)?-0.2f:0.0f;

    float s0,s1,s2,s3,s4,s5,s6,s7,s8,s9;
    { const float* sp = states + (size_t)b*NT*NS;
      s0=sp[0];s1=sp[1];s2=sp[2];s3=sp[3];s4=sp[4];
      s5=sp[5];s6=sp[6];s7=sp[7];s8=sp[8];s9=sp[9]; }

    float* spo = out + (size_t)b*NTO*NS + l;
    float* ipo = out + (size_t)NB*NTO*NS + (size_t)b*NTO*7 + l;

    const ushort4* xp = (const ushort4*)(xws + ((size_t)b*16 + l)*NT);
    ushort4 xa = xp[0], xb = xp[1];

    float h = 0.f;

#define BSLOT(T) (((T)&7)<<6)

#define RNN(XWV)  h = ftanh(rotdot16_4(h, whr, (XWV)))

#define MLP(T) do { \
    float t1 = ftanh(rotdot16_4(h, d1r, d1bl)); \
    float dv = rotdot16_4(t1, d2r, d2bl); \
    db[BSLOT(T) + lane] = fmaf(Aa, fsig(Ba*dv), Ca); \
} while(0)

#define BUDGET(T) do { \
    const float* rb = db + BSLOT(T) + (g<<4); \
    float4 w0 = *(const float4*)rb; \
    float4 w1 = *(const float4*)(rb+4); \
    float2 w2 = *(const float2*)(rb+8); \
    float rev   = fmaf(s0, w0.x, s0); \
    float cogs  = w0.y * rev; \
    float opex  = w0.z * rev; \
    float dep   = w0.w * s4; \
    float inte  = w2.y * s6; \
    float ebt   = (((rev - cogs) - opex) - dep) - inte; \
    float tax   = w2.x * fmaxf(ebt, 0.0f); \
    float ni    = ebt - tax; \
    float arn   = w1.y * rev; \
    float invn  = w1.z * cogs; \
    float apn   = w1.w * cogs; \
    float capex = w1.x * rev; \
    float ppen  = (s4 + capex) - dep; \
    float cashn = (((((s1 + ni) + dep) - capex) - (arn - s2)) - (invn - s3)) + (apn - s5); \
    float ren   = s8 + ni; \
    s0=rev; s1=cashn; s2=arn; s3=invn; s4=ppen; s5=apn; s8=ren; \
    float sv = (l==0)?rev:(l==1)?cashn:(l==2)?arn:(l==3)?invn:(l==4)?ppen: \
               (l==5)?apn:(l==6)?s6:(l==7)?s7:(l==8)?ren:s9; \
    float iv = (l==0)?rev:(l==1)?cogs:(l==2)?opex:(l==3)?dep:(l==4)?inte:(l==5)?tax:ni; \
    if (l < NS) *spo = sv; \
    if (l < 7)  *ipo = iv; \
    spo += NS; ipo += 7; \
} while(0)

#define XH(V,U) __half2float(__ushort_as_half((U)==0?(V).x:(U)==1?(V).y:(U)==2?(V).z:(V).w))

    // ---- prologue: tt=0 covers t=0..3 (t=0 has no MLP; budgets start at t=1) ----
    {
        ushort4 xc = xa; xa = xb; xb = xp[2];
        RNN(XH(xc,0));                           // t=0
        RNN(XH(xc,1)); MLP(1);                   // t=1
        RNN(XH(xc,2)); BUDGET(1); MLP(2);        // t=2
        RNN(XH(xc,3)); BUDGET(2); MLP(3);        // t=3
    }

    // ---- main loop: tt=1..63, t=4tt..4tt+3; budget skewed by one step ----
    #pragma unroll 1
    for (int tt = 1; tt < 64; ++tt) {
        ushort4 xc = xa; xa = xb;
        if (tt < 62) xb = xp[tt+2];
        #pragma unroll
        for (int u = 0; u < 4; ++u) {
            const int t = tt*4 + u;
            RNN(XH(xc,u));
            BUDGET(t-1);
            MLP(t);
        }
    }

    // ---- epilogue: budget for t=255 ----
    BUDGET(255);

#undef XH
#undef BUDGET
#undef MLP
#undef RNN
#undef BSLOT
}

extern "C" void kernel_launch(void* const* d_in, const int* in_sizes, int n_in,
                              void* d_out, int out_size, void* d_ws, size_t ws_size,
                              hipStream_t stream) {
    (void)in_sizes; (void)n_in; (void)ws_size; (void)out_size;
    __half* xws = (__half*)d_ws;   // 4096*16*256 fp16 = 33.5 MB
    xw_kernel<<<NB/4, 256, 0, stream>>>(
        (const float*)d_in[1],  // covariates_seq
        (const float*)d_in[2],  // ln_gamma
        (const float*)d_in[3],  // ln_beta
        (const float*)d_in[4],  // rnn_wx
        (const float*)d_in[6],  // rnn_b
        xws);
    scan_kernel<<<NB/4, 64, 0, stream>>>(
        (const float*)d_in[0],  // states_seq
        xws,
        (const float*)d_in[5],  // rnn_wh
        (const float*)d_in[7],  // d1_w
        (const float*)d_in[8],  // d1_b
        (const float*)d_in[9],  // d2_w
        (const float*)d_in[10], // d2_b
        (float*)d_out);
}

// Round 6
// 583.495 us; speedup vs baseline: 1.0647x; 1.0094x over previous
//
#include <hip/hip_runtime.h>
#include <hip/hip_fp16.h>

#define NB 4096
#define NT 256
#define NC 64
#define NH 16
#define NS 10
#define NTO 255

__device__ __forceinline__ float fast_rcp(float x){ return __builtin_amdgcn_rcpf(x); }
__device__ __forceinline__ float fast_rsq(float x){ return __builtin_amdgcn_rsqf(x); }
__device__ __forceinline__ float fsig(float x){ return fast_rcp(1.0f + __expf(-x)); }
__device__ __forceinline__ float ftanh(float x){
    float e = __expf(2.0f*x);
    return fmaf(-2.0f, fast_rcp(e + 1.0f), 1.0f);
}

// row_ror:R within each 16-lane row: lane l receives lane (l-R)&15's value. VALU pipe, no LDS.
template<int R>
__device__ __forceinline__ float rotf(float x){
    return __int_as_float(__builtin_amdgcn_update_dpp(
        0, __float_as_int(x), 0x120 + R, 0xF, 0xF, true));
}
// butterfly sum over the 16-lane row, result broadcast to all 16 lanes
__device__ __forceinline__ float row_bcast_sum(float x){
    x += rotf<8>(x);
    x += rotf<4>(x);
    x += rotf<2>(x);
    x += rotf<1>(x);
    return x;
}

// ===================== K1: xw = LN(cov) @ (gamma-folded wx) + (beta@wx + rnn_b) =====================
// (unchanged from the proven baseline)
__global__ __launch_bounds__(256, 4) void xw_kernel(
    const float* __restrict__ cov, const float* __restrict__ lng,
    const float* __restrict__ lnb, const float* __restrict__ wx,
    const float* __restrict__ rnb, __half* __restrict__ xws)
{
    const int wid  = threadIdx.x >> 6;
    const int lane = threadIdx.x & 63;
    const int g = lane >> 4, l = lane & 15;
    const int b = (blockIdx.x << 2) + wid;

    float gwr[64];
    #pragma unroll
    for (int r = 0; r < 16; ++r) {
        int c0 = 4 * ((l - r) & 15);
        #pragma unroll
        for (int j = 0; j < 4; ++j)
            gwr[4*r+j] = lng[c0+j] * wx[(c0+j)*NH + l];
    }
    float bwb = rnb[l];
    #pragma unroll
    for (int c = 0; c < NC; ++c) bwb = fmaf(lnb[c], wx[c*NH + l], bwb);

    const float4* gp = (const float4*)cov + (size_t)b*NT*16 + g*16 + l;
    __half* op = xws + ((size_t)b*16 + l)*NT + g;

    float4 cur = gp[0];
    float4 nxt = gp[64];
    #pragma unroll 2
    for (int it = 0; it < 64; ++it) {
        float4 x = cur;
        cur = nxt;
        if (it < 62) nxt = gp[(size_t)(it+2)*64];
        float ss = (x.x + x.y) + (x.z + x.w);
        float sq = fmaf(x.x,x.x, fmaf(x.y,x.y, fmaf(x.z,x.z, x.w*x.w)));
        ss = row_bcast_sum(ss);
        sq = row_bcast_sum(sq);
        float mu  = ss * (1.0f/64.0f);
        float var = fmaf(-mu, mu, sq * (1.0f/64.0f));
        float rs  = fast_rsq(var + 0.001f);
        float nmu = -mu * rs;
        float x0 = fmaf(x.x, rs, nmu), x1 = fmaf(x.y, rs, nmu);
        float x2 = fmaf(x.z, rs, nmu), x3 = fmaf(x.w, rs, nmu);
        float a0 = bwb, a1 = 0.f, a2 = 0.f, a3 = 0.f;
        a0 = fmaf(x0, gwr[0], a0); a1 = fmaf(x1, gwr[1], a1);
        a2 = fmaf(x2, gwr[2], a2); a3 = fmaf(x3, gwr[3], a3);
#define ROTSTEP(R) { float r0=rotf<R>(x0), r1=rotf<R>(x1), r2=rotf<R>(x2), r3=rotf<R>(x3); \
        a0=fmaf(r0,gwr[4*R+0],a0); a1=fmaf(r1,gwr[4*R+1],a1); \
        a2=fmaf(r2,gwr[4*R+2],a2); a3=fmaf(r3,gwr[4*R+3],a3); }
        ROTSTEP(1)  ROTSTEP(2)  ROTSTEP(3)  ROTSTEP(4)  ROTSTEP(5)
        ROTSTEP(6)  ROTSTEP(7)  ROTSTEP(8)  ROTSTEP(9)  ROTSTEP(10)
        ROTSTEP(11) ROTSTEP(12) ROTSTEP(13) ROTSTEP(14) ROTSTEP(15)
#undef ROTSTEP
        float xw = (a0+a1)+(a2+a3);
        op[it*4] = __float2half(xw);
    }
}

// ===================== K2: 4-stage skewed, instruction-interleaved scan =====================
// 1024 blocks x 1 wave; lane = g*16+l, g = batch-in-wave, l = hidden index.
// Per iteration j (one basic block, source-interleaved for in-order issue):
//   S4(j-3): ds_read act (written LAST iteration -> LDS latency fully hidden) + budget + stores
//   S1(j):   RNN rotdot+tanh -> h(j)      [the only true serial chain]
//   S2(j-1): d1 rotdot+tanh -> t1(j-1)    [SAME input h(j-1): shares the 15 DPP rots with S1]
//   S3(j-2): d2 rotdot+sig -> ds_write    [DPPs placed between S1/S2 exps and rcps as filler]
__global__ __launch_bounds__(64, 1) void scan_kernel(
    const float* __restrict__ states, const __half* __restrict__ xws,
    const float* __restrict__ wh,     const float* __restrict__ d1w,
    const float* __restrict__ d1b,    const float* __restrict__ d2w,
    const float* __restrict__ d2b,    float* __restrict__ out)
{
    const int lane = threadIdx.x;
    const int g = lane >> 4, l = lane & 15;
    const int b = (blockIdx.x << 2) + g;

    __shared__ __align__(16) float db[8*64];   // 8-slot rotating act broadcast, 2 KB

    float whr[NH], d1r[NH], d2r[NH];
    #pragma unroll
    for (int r = 0; r < NH; ++r) {
        int src = (l - r) & 15;
        whr[r] = wh[src*NH + l];
        d1r[r] = d1w[src*NH + l];
        d2r[r] = d2w[src*NH + l];
    }
    const float d1bl = d1b[l], d2bl = d2b[l];
    // per-lane driver activation: act = A*sigmoid(B*x) + C  (lane0: 0.2*tanh via sig)
    const float Aa = (l==0)?0.4f:(l==2)?0.5f:(l==3)?0.1f:(l==4)?0.2f:(l==8)?0.35f:(l==9)?0.1f:1.0f;
    const float Ba = (l==0)?2.0f:1.0f;
    const float Ca = (l==0)?-0.2f:0.0f;

    float s0,s1,s2,s3,s4,s5,s6,s7,s8,s9;
    { const float* sp = states + (size_t)b*NT*NS;
      s0=sp[0];s1=sp[1];s2=sp[2];s3=sp[3];s4=sp[4];
      s5=sp[5];s6=sp[6];s7=sp[7];s8=sp[8];s9=sp[9]; }

    float* spo = out + (size_t)b*NTO*NS + l;
    float* ipo = out + (size_t)NB*NTO*NS + (size_t)b*NTO*7 + l;

    const ushort4* xp = (const ushort4*)(xws + ((size_t)b*16 + l)*NT);
    ushort4 xa = xp[0], xb = xp[1];

    float h = 0.f;     // h(j-1) entering iteration j
    float t1p = 0.f;   // t1(j-2) entering iteration j

#define XH(V,U) __half2float(__ushort_as_half((U)==0?(V).x:(U)==1?(V).y:(U)==2?(V).z:(V).w))

#define STEP(J, XWV, S1F, S2F, S3F, S4F) do { \
    /* --- S4 loads issued first: data written one full iteration ago --- */ \
    float4 w0{}, w1{}; float2 w2{}; \
    if (S4F) { const float* rb = db + ((((J)-3)&7)<<6) + (g<<4); \
        w0 = *(const float4*)rb; w1 = *(const float4*)(rb+4); w2 = *(const float2*)(rb+8); } \
    float hn = h, t1n = t1p; \
    float eR = 0.f, eD = 0.f, sR = 0.f, sD = 0.f; \
    if (S1F || S2F) { \
        float r1=rotf<1>(h),  r2=rotf<2>(h),  r3=rotf<3>(h),  r4=rotf<4>(h); \
        float r5=rotf<5>(h),  r6=rotf<6>(h),  r7=rotf<7>(h),  r8=rotf<8>(h); \
        float r9=rotf<9>(h),  r10=rotf<10>(h), r11=rotf<11>(h), r12=rotf<12>(h); \
        float r13=rotf<13>(h), r14=rotf<14>(h), r15=rotf<15>(h); \
        float aR0=(XWV), aR1=0.f, aR2=0.f, aR3=0.f; \
        float aD0=d1bl,  aD1=0.f, aD2=0.f, aD3=0.f; \
        if (S1F) aR0=fmaf(h,  whr[0], aR0);   if (S2F) aD0=fmaf(h,  d1r[0], aD0); \
        if (S1F) aR1=fmaf(r1, whr[1], aR1);   if (S2F) aD1=fmaf(r1, d1r[1], aD1); \
        if (S1F) aR2=fmaf(r2, whr[2], aR2);   if (S2F) aD2=fmaf(r2, d1r[2], aD2); \
        if (S1F) aR3=fmaf(r3, whr[3], aR3);   if (S2F) aD3=fmaf(r3, d1r[3], aD3); \
        if (S1F) aR0=fmaf(r4, whr[4], aR0);   if (S2F) aD0=fmaf(r4, d1r[4], aD0); \
        if (S1F) aR1=fmaf(r5, whr[5], aR1);   if (S2F) aD1=fmaf(r5, d1r[5], aD1); \
        if (S1F) aR2=fmaf(r6, whr[6], aR2);   if (S2F) aD2=fmaf(r6, d1r[6], aD2); \
        if (S1F) aR3=fmaf(r7, whr[7], aR3);   if (S2F) aD3=fmaf(r7, d1r[7], aD3); \
        if (S1F) aR0=fmaf(r8, whr[8], aR0);   if (S2F) aD0=fmaf(r8, d1r[8], aD0); \
        if (S1F) aR1=fmaf(r9, whr[9], aR1);   if (S2F) aD1=fmaf(r9, d1r[9], aD1); \
        if (S1F) aR2=fmaf(r10,whr[10],aR2);   if (S2F) aD2=fmaf(r10,d1r[10],aD2); \
        if (S1F) aR3=fmaf(r11,whr[11],aR3);   if (S2F) aD3=fmaf(r11,d1r[11],aD3); \
        if (S1F) aR0=fmaf(r12,whr[12],aR0);   if (S2F) aD0=fmaf(r12,d1r[12],aD0); \
        if (S1F) aR1=fmaf(r13,whr[13],aR1);   if (S2F) aD1=fmaf(r13,d1r[13],aD1); \
        if (S1F) aR2=fmaf(r14,whr[14],aR2);   if (S2F) aD2=fmaf(r14,d1r[14],aD2); \
        if (S1F) aR3=fmaf(r15,whr[15],aR3);   if (S2F) aD3=fmaf(r15,d1r[15],aD3); \
        if (S1F) sR = (aR0+aR1)+(aR2+aR3); \
        if (S2F) sD = (aD0+aD1)+(aD2+aD3); \
        if (S1F) eR = __expf(2.0f*sR); \
        if (S2F) eD = __expf(2.0f*sD); \
    } \
    /* --- S3 DPPs: independent filler between exps and rcps --- */ \
    float dv = 0.f; \
    if (S3F) { \
        float q1=rotf<1>(t1p),  q2=rotf<2>(t1p),  q3=rotf<3>(t1p),  q4=rotf<4>(t1p); \
        float q5=rotf<5>(t1p),  q6=rotf<6>(t1p),  q7=rotf<7>(t1p),  q8=rotf<8>(t1p); \
        float q9=rotf<9>(t1p),  q10=rotf<10>(t1p), q11=rotf<11>(t1p), q12=rotf<12>(t1p); \
        float q13=rotf<13>(t1p), q14=rotf<14>(t1p), q15=rotf<15>(t1p); \
        float aS0=d2bl, aS1=0.f, aS2=0.f, aS3=0.f; \
        aS0=fmaf(t1p,d2r[0],aS0); aS1=fmaf(q1, d2r[1], aS1); \
        aS2=fmaf(q2, d2r[2], aS2); aS3=fmaf(q3, d2r[3], aS3); \
        aS0=fmaf(q4, d2r[4], aS0); aS1=fmaf(q5, d2r[5], aS1); \
        aS2=fmaf(q6, d2r[6], aS2); aS3=fmaf(q7, d2r[7], aS3); \
        aS0=fmaf(q8, d2r[8], aS0); aS1=fmaf(q9, d2r[9], aS1); \
        aS2=fmaf(q10,d2r[10],aS2); aS3=fmaf(q11,d2r[11],aS3); \
        aS0=fmaf(q12,d2r[12],aS0); aS1=fmaf(q13,d2r[13],aS1); \
        aS2=fmaf(q14,d2r[14],aS2); aS3=fmaf(q15,d2r[15],aS3); \
        dv = (aS0+aS1)+(aS2+aS3); \
    } \
    /* --- S1/S2 rcps (exp latency now covered by S3 work above) --- */ \
    if (S1F) hn  = fmaf(-2.0f, fast_rcp(eR+1.0f), 1.0f); \
    if (S2F) t1n = fmaf(-2.0f, fast_rcp(eD+1.0f), 1.0f); \
    if (S3F) { \
        float es = __expf(-Ba*dv); \
        float act = fmaf(Aa, fast_rcp(1.0f+es), Ca); \
        db[((((J)-2)&7)<<6) + lane] = act; \
    } \
    if (S4F) { \
        float rev   = fmaf(s0, w0.x, s0); \
        float cogs  = w0.y * rev; \
        float opex  = w0.z * rev; \
        float dep   = w0.w * s4; \
        float inte  = w2.y * s6; \
        float ebt   = (((rev - cogs) - opex) - dep) - inte; \
        float tax   = w2.x * fmaxf(ebt, 0.0f); \
        float ni    = ebt - tax; \
        float arn   = w1.y * rev; \
        float invn  = w1.z * cogs; \
        float apn   = w1.w * cogs; \
        float capex = w1.x * rev; \
        float ppen  = (s4 + capex) - dep; \
        float cashn = (((((s1 + ni) + dep) - capex) - (arn - s2)) - (invn - s3)) + (apn - s5); \
        float ren   = s8 + ni; \
        s0=rev; s1=cashn; s2=arn; s3=invn; s4=ppen; s5=apn; s8=ren; \
        float sv = (l==0)?rev:(l==1)?cashn:(l==2)?arn:(l==3)?invn:(l==4)?ppen: \
                   (l==5)?apn:(l==6)?s6:(l==7)?s7:(l==8)?ren:s9; \
        float iv = (l==0)?rev:(l==1)?cogs:(l==2)?opex:(l==3)?dep:(l==4)?inte:(l==5)?tax:ni; \
        if (l < NS) *spo = sv; \
        if (l < 7)  *ipo = iv; \
        spo += NS; ipo += 7; \
    } \
    h = hn; t1p = t1n; \
} while(0)

    // ---- prologue: j=0..3 (fill the pipeline) ----
    {
        ushort4 xc = xa; xa = xb; xb = xp[2];
        h = ftanh(XH(xc,0));                    // j=0: S1 only (h @ wh term is zero)
        STEP(1, XH(xc,1), 1,0,0,0);             // j=1: S1          (MLP(0) unused)
        STEP(2, XH(xc,2), 1,1,0,0);             // j=2: S1,S2(1)
        STEP(3, XH(xc,3), 1,1,1,0);             // j=3: S1,S2(2),S3(1)
    }

    // ---- main loop: j = 4tt+u, tt=1..63 -> j=4..255, all four stages live ----
    #pragma unroll 1
    for (int tt = 1; tt < 64; ++tt) {
        ushort4 xc = xa; xa = xb;
        if (tt < 62) xb = xp[tt+2];
        STEP(4*tt+0, XH(xc,0), 1,1,1,1);
        STEP(4*tt+1, XH(xc,1), 1,1,1,1);
        STEP(4*tt+2, XH(xc,2), 1,1,1,1);
        STEP(4*tt+3, XH(xc,3), 1,1,1,1);
    }

    // ---- drain: j=256..258 ----
    STEP(256, 0.0f, 0,1,1,1);    // S2(255), S3(254), S4(253)
    STEP(257, 0.0f, 0,0,1,1);    // S3(255), S4(254)
    STEP(258, 0.0f, 0,0,0,1);    // S4(255)

#undef STEP
#undef XH
}

extern "C" void kernel_launch(void* const* d_in, const int* in_sizes, int n_in,
                              void* d_out, int out_size, void* d_ws, size_t ws_size,
                              hipStream_t stream) {
    (void)in_sizes; (void)n_in; (void)ws_size; (void)out_size;
    __half* xws = (__half*)d_ws;   // 4096*16*256 fp16 = 33.5 MB
    xw_kernel<<<NB/4, 256, 0, stream>>>(
        (const float*)d_in[1],  // covariates_seq
        (const float*)d_in[2],  // ln_gamma
        (const float*)d_in[3],  // ln_beta
        (const float*)d_in[4],  // rnn_wx
        (const float*)d_in[6],  // rnn_b
        xws);
    scan_kernel<<<NB/4, 64, 0, stream>>>(
        (const float*)d_in[0],  // states_seq
        xws,
        (const float*)d_in[5],  // rnn_wh
        (const float*)d_in[7],  // d1_w
        (const float*)d_in[8],  // d1_b
        (const float*)d_in[9],  // d2_w
        (const float*)d_in[10], // d2_b
        (float*)d_out);
}

// Round 7
// 565.467 us; speedup vs baseline: 1.0986x; 1.0319x over previous
//
#include <hip/hip_runtime.h>
#include <hip/hip_fp16.h>

#define NB 4096
#define NT 256
#define NC 64
#define NH 16
#define NS 10
#define NTO 255

__device__ __forceinline__ float fast_rcp(float x){ return __builtin_amdgcn_rcpf(x); }
__device__ __forceinline__ float fast_rsq(float x){ return __builtin_amdgcn_rsqf(x); }
__device__ __forceinline__ float ftanh(float x){
    float e = __expf(2.0f*x);
    return fmaf(-2.0f, fast_rcp(e + 1.0f), 1.0f);
}

// row_ror:R within each 16-lane row: lane l receives lane (l-R)&15's value. VALU pipe, no LDS.
template<int R>
__device__ __forceinline__ float rotf(float x){
    return __int_as_float(__builtin_amdgcn_update_dpp(
        0, __float_as_int(x), 0x120 + R, 0xF, 0xF, true));
}
// butterfly sum over the 16-lane row, result broadcast to all 16 lanes
__device__ __forceinline__ float row_bcast_sum(float x){
    x += rotf<8>(x);
    x += rotf<4>(x);
    x += rotf<2>(x);
    x += rotf<1>(x);
    return x;
}

// ===================== K1: xw = LN(cov) @ (gamma-folded wx) + (beta@wx + rnn_b) =====================
// (unchanged from the proven baseline)
__global__ __launch_bounds__(256, 4) void xw_kernel(
    const float* __restrict__ cov, const float* __restrict__ lng,
    const float* __restrict__ lnb, const float* __restrict__ wx,
    const float* __restrict__ rnb, __half* __restrict__ xws)
{
    const int wid  = threadIdx.x >> 6;
    const int lane = threadIdx.x & 63;
    const int g = lane >> 4, l = lane & 15;
    const int b = (blockIdx.x << 2) + wid;

    float gwr[64];
    #pragma unroll
    for (int r = 0; r < 16; ++r) {
        int c0 = 4 * ((l - r) & 15);
        #pragma unroll
        for (int j = 0; j < 4; ++j)
            gwr[4*r+j] = lng[c0+j] * wx[(c0+j)*NH + l];
    }
    float bwb = rnb[l];
    #pragma unroll
    for (int c = 0; c < NC; ++c) bwb = fmaf(lnb[c], wx[c*NH + l], bwb);

    const float4* gp = (const float4*)cov + (size_t)b*NT*16 + g*16 + l;
    __half* op = xws + ((size_t)b*16 + l)*NT + g;

    float4 cur = gp[0];
    float4 nxt = gp[64];
    #pragma unroll 2
    for (int it = 0; it < 64; ++it) {
        float4 x = cur;
        cur = nxt;
        if (it < 62) nxt = gp[(size_t)(it+2)*64];
        float ss = (x.x + x.y) + (x.z + x.w);
        float sq = fmaf(x.x,x.x, fmaf(x.y,x.y, fmaf(x.z,x.z, x.w*x.w)));
        ss = row_bcast_sum(ss);
        sq = row_bcast_sum(sq);
        float mu  = ss * (1.0f/64.0f);
        float var = fmaf(-mu, mu, sq * (1.0f/64.0f));
        float rs  = fast_rsq(var + 0.001f);
        float nmu = -mu * rs;
        float x0 = fmaf(x.x, rs, nmu), x1 = fmaf(x.y, rs, nmu);
        float x2 = fmaf(x.z, rs, nmu), x3 = fmaf(x.w, rs, nmu);
        float a0 = bwb, a1 = 0.f, a2 = 0.f, a3 = 0.f;
        a0 = fmaf(x0, gwr[0], a0); a1 = fmaf(x1, gwr[1], a1);
        a2 = fmaf(x2, gwr[2], a2); a3 = fmaf(x3, gwr[3], a3);
#define ROTSTEP(R) { float r0=rotf<R>(x0), r1=rotf<R>(x1), r2=rotf<R>(x2), r3=rotf<R>(x3); \
        a0=fmaf(r0,gwr[4*R+0],a0); a1=fmaf(r1,gwr[4*R+1],a1); \
        a2=fmaf(r2,gwr[4*R+2],a2); a3=fmaf(r3,gwr[4*R+3],a3); }
        ROTSTEP(1)  ROTSTEP(2)  ROTSTEP(3)  ROTSTEP(4)  ROTSTEP(5)
        ROTSTEP(6)  ROTSTEP(7)  ROTSTEP(8)  ROTSTEP(9)  ROTSTEP(10)
        ROTSTEP(11) ROTSTEP(12) ROTSTEP(13) ROTSTEP(14) ROTSTEP(15)
#undef ROTSTEP
        float xw = (a0+a1)+(a2+a3);
        op[it*4] = __float2half(xw);
    }
}

// ===================== K2: producer/consumer two-wave scan =====================
// 1024 blocks x 128 threads (2 waves) = 2048 waves -> 2 waves/SIMD.
// Wave 0 (producer): RNN + driver MLP for 4 batches, S1/S2/S3 skewed as in the
//   previous version, writing act(t) into a 16-slot LDS ring (slot t&15).
// Wave 1 (consumer): cash-budget scan + output stores, reading acts one phase
//   behind (ring-disjoint: any 16 consecutive act indices cover slots 0..15).
// One __syncthreads per 8-step group publishes producer writes (34 barriers).
__global__ __launch_bounds__(128, 1) void scan_pc(
    const float* __restrict__ states, const __half* __restrict__ xws,
    const float* __restrict__ wh,     const float* __restrict__ d1w,
    const float* __restrict__ d1b,    const float* __restrict__ d2w,
    const float* __restrict__ d2b,    float* __restrict__ out)
{
    const int tid  = threadIdx.x;
    const int wid  = tid >> 6;
    const int lane = tid & 63;
    const int g = lane >> 4, l = lane & 15;
    const int b = (blockIdx.x << 2) + g;

    __shared__ __align__(16) float db[16*64];   // 16-slot act ring, 4 KB

    // ---- producer state (wave 0 only; dead for wave 1) ----
    float whr[NH], d1r[NH], d2r[NH];
    float d1bl = 0.f, d2bl = 0.f;
    float Aa = 1.f, Ba = 1.f, Ca = 0.f;
    float h = 0.f, t1p = 0.f;
    const ushort4* xp = (const ushort4*)(xws + ((size_t)b*16 + l)*NT);
    ushort4 xA{}, xB{}, xC{}, xD{};

    // ---- consumer state (wave 1 only; dead for wave 0) ----
    float s0=0,s1=0,s2=0,s3=0,s4=0,s5=0,s6=0,s7=0,s8=0,s9=0;
    float* spo = out + (size_t)b*NTO*NS + l;
    float* ipo = out + (size_t)NB*NTO*NS + (size_t)b*NTO*7 + l;

    if (wid == 0) {
        #pragma unroll
        for (int r = 0; r < NH; ++r) {
            int src = (l - r) & 15;
            whr[r] = wh[src*NH + l];
            d1r[r] = d1w[src*NH + l];
            d2r[r] = d2w[src*NH + l];
        }
        d1bl = d1b[l]; d2bl = d2b[l];
        Aa = (l==0)?0.4f:(l==2)?0.5f:(l==3)?0.1f:(l==4)?0.2f:(l==8)?0.35f:(l==9)?0.1f:1.0f;
        Ba = (l==0)?2.0f:1.0f;
        Ca = (l==0)?-0.2f:0.0f;
        xA = xp[0]; xB = xp[1]; xC = xp[2]; xD = xp[3];
    } else {
        const float* sp = states + (size_t)b*NT*NS;
        s0=sp[0];s1=sp[1];s2=sp[2];s3=sp[3];s4=sp[4];
        s5=sp[5];s6=sp[6];s7=sp[7];s8=sp[8];s9=sp[9];
    }

#define XH(V,U) __half2float(__ushort_as_half((U)==0?(V).x:(U)==1?(V).y:(U)==2?(V).z:(V).w))

// producer step: S1 = RNN h(j) (shares h-rotations with S2), S2 = d1+tanh -> t1(j-1),
// S3 = d2+sig on t1p=t1(j-2) -> act ACTI=j-2 into ring slot (ACTI&15).
#define PSTEP(ACTI, XWV, S1F, S2F, S3F) do { \
    float hn = h, t1n = t1p; \
    float eR = 0.f, eD = 0.f, sR = 0.f, sD = 0.f; \
    if (S1F || S2F) { \
        float r1=rotf<1>(h),  r2=rotf<2>(h),  r3=rotf<3>(h),  r4=rotf<4>(h); \
        float r5=rotf<5>(h),  r6=rotf<6>(h),  r7=rotf<7>(h),  r8=rotf<8>(h); \
        float r9=rotf<9>(h),  r10=rotf<10>(h), r11=rotf<11>(h), r12=rotf<12>(h); \
        float r13=rotf<13>(h), r14=rotf<14>(h), r15=rotf<15>(h); \
        float aR0=(XWV), aR1=0.f, aR2=0.f, aR3=0.f; \
        float aD0=d1bl,  aD1=0.f, aD2=0.f, aD3=0.f; \
        if (S1F) aR0=fmaf(h,  whr[0], aR0);   if (S2F) aD0=fmaf(h,  d1r[0], aD0); \
        if (S1F) aR1=fmaf(r1, whr[1], aR1);   if (S2F) aD1=fmaf(r1, d1r[1], aD1); \
        if (S1F) aR2=fmaf(r2, whr[2], aR2);   if (S2F) aD2=fmaf(r2, d1r[2], aD2); \
        if (S1F) aR3=fmaf(r3, whr[3], aR3);   if (S2F) aD3=fmaf(r3, d1r[3], aD3); \
        if (S1F) aR0=fmaf(r4, whr[4], aR0);   if (S2F) aD0=fmaf(r4, d1r[4], aD0); \
        if (S1F) aR1=fmaf(r5, whr[5], aR1);   if (S2F) aD1=fmaf(r5, d1r[5], aD1); \
        if (S1F) aR2=fmaf(r6, whr[6], aR2);   if (S2F) aD2=fmaf(r6, d1r[6], aD2); \
        if (S1F) aR3=fmaf(r7, whr[7], aR3);   if (S2F) aD3=fmaf(r7, d1r[7], aD3); \
        if (S1F) aR0=fmaf(r8, whr[8], aR0);   if (S2F) aD0=fmaf(r8, d1r[8], aD0); \
        if (S1F) aR1=fmaf(r9, whr[9], aR1);   if (S2F) aD1=fmaf(r9, d1r[9], aD1); \
        if (S1F) aR2=fmaf(r10,whr[10],aR2);   if (S2F) aD2=fmaf(r10,d1r[10],aD2); \
        if (S1F) aR3=fmaf(r11,whr[11],aR3);   if (S2F) aD3=fmaf(r11,d1r[11],aD3); \
        if (S1F) aR0=fmaf(r12,whr[12],aR0);   if (S2F) aD0=fmaf(r12,d1r[12],aD0); \
        if (S1F) aR1=fmaf(r13,whr[13],aR1);   if (S2F) aD1=fmaf(r13,d1r[13],aD1); \
        if (S1F) aR2=fmaf(r14,whr[14],aR2);   if (S2F) aD2=fmaf(r14,d1r[14],aD2); \
        if (S1F) aR3=fmaf(r15,whr[15],aR3);   if (S2F) aD3=fmaf(r15,d1r[15],aD3); \
        if (S1F) sR = (aR0+aR1)+(aR2+aR3); \
        if (S2F) sD = (aD0+aD1)+(aD2+aD3); \
        if (S1F) eR = __expf(2.0f*sR); \
        if (S2F) eD = __expf(2.0f*sD); \
    } \
    float dv = 0.f; \
    if (S3F) { \
        float q1=rotf<1>(t1p),  q2=rotf<2>(t1p),  q3=rotf<3>(t1p),  q4=rotf<4>(t1p); \
        float q5=rotf<5>(t1p),  q6=rotf<6>(t1p),  q7=rotf<7>(t1p),  q8=rotf<8>(t1p); \
        float q9=rotf<9>(t1p),  q10=rotf<10>(t1p), q11=rotf<11>(t1p), q12=rotf<12>(t1p); \
        float q13=rotf<13>(t1p), q14=rotf<14>(t1p), q15=rotf<15>(t1p); \
        float aS0=d2bl, aS1=0.f, aS2=0.f, aS3=0.f; \
        aS0=fmaf(t1p,d2r[0],aS0); aS1=fmaf(q1, d2r[1], aS1); \
        aS2=fmaf(q2, d2r[2], aS2); aS3=fmaf(q3, d2r[3], aS3); \
        aS0=fmaf(q4, d2r[4], aS0); aS1=fmaf(q5, d2r[5], aS1); \
        aS2=fmaf(q6, d2r[6], aS2); aS3=fmaf(q7, d2r[7], aS3); \
        aS0=fmaf(q8, d2r[8], aS0); aS1=fmaf(q9, d2r[9], aS1); \
        aS2=fmaf(q10,d2r[10],aS2); aS3=fmaf(q11,d2r[11],aS3); \
        aS0=fmaf(q12,d2r[12],aS0); aS1=fmaf(q13,d2r[13],aS1); \
        aS2=fmaf(q14,d2r[14],aS2); aS3=fmaf(q15,d2r[15],aS3); \
        dv = (aS0+aS1)+(aS2+aS3); \
    } \
    if (S1F) hn  = fmaf(-2.0f, fast_rcp(eR+1.0f), 1.0f); \
    if (S2F) t1n = fmaf(-2.0f, fast_rcp(eD+1.0f), 1.0f); \
    if (S3F) { \
        float es = __expf(-Ba*dv); \
        float act = fmaf(Aa, fast_rcp(1.0f+es), Ca); \
        db[(((ACTI)&15)<<6) + lane] = act; \
    } \
    h = hn; t1p = t1n; \
} while(0)

// full 8-step producer group G (j = 8G..8G+7, acts 8G-2..8G+5)
#define PGROUP(G) do { \
    ushort4 x0 = xA, x1 = xB; xA = xC; xB = xD; \
    if (2*(G)+5 < 64) { xC = xp[2*(G)+4]; xD = xp[2*(G)+5]; } \
    const int jb = 8*(G); \
    PSTEP(jb-2, XH(x0,0), 1,1,1); \
    PSTEP(jb-1, XH(x0,1), 1,1,1); \
    PSTEP(jb+0, XH(x0,2), 1,1,1); \
    PSTEP(jb+1, XH(x0,3), 1,1,1); \
    PSTEP(jb+2, XH(x1,0), 1,1,1); \
    PSTEP(jb+3, XH(x1,1), 1,1,1); \
    PSTEP(jb+4, XH(x1,2), 1,1,1); \
    PSTEP(jb+5, XH(x1,3), 1,1,1); \
} while(0)

// consumer budget step for act index T (ring slot T&15)
#define CSTEP(T) do { \
    const float* rb = db + (((T)&15)<<6) + (g<<4); \
    float4 w0 = *(const float4*)rb; \
    float4 w1 = *(const float4*)(rb+4); \
    float2 w2 = *(const float2*)(rb+8); \
    float rev   = fmaf(s0, w0.x, s0); \
    float cogs  = w0.y * rev; \
    float opex  = w0.z * rev; \
    float dep   = w0.w * s4; \
    float inte  = w2.y * s6; \
    float ebt   = (((rev - cogs) - opex) - dep) - inte; \
    float tax   = w2.x * fmaxf(ebt, 0.0f); \
    float ni    = ebt - tax; \
    float arn   = w1.y * rev; \
    float invn  = w1.z * cogs; \
    float apn   = w1.w * cogs; \
    float capex = w1.x * rev; \
    float ppen  = (s4 + capex) - dep; \
    float cashn = (((((s1 + ni) + dep) - capex) - (arn - s2)) - (invn - s3)) + (apn - s5); \
    float ren   = s8 + ni; \
    s0=rev; s1=cashn; s2=arn; s3=invn; s4=ppen; s5=apn; s8=ren; \
    float sv = (l==0)?rev:(l==1)?cashn:(l==2)?arn:(l==3)?invn:(l==4)?ppen: \
               (l==5)?apn:(l==6)?s6:(l==7)?s7:(l==8)?ren:s9; \
    float iv = (l==0)?rev:(l==1)?cogs:(l==2)?opex:(l==3)?dep:(l==4)?inte:(l==5)?tax:ni; \
    if (l < NS) *spo = sv; \
    if (l < 7)  *ipo = iv; \
    spo += NS; ipo += 7; \
} while(0)

    // ---- phase 0: producer group 0 (j=0..7, acts 1..5) ----
    if (wid == 0) {
        ushort4 x0 = xA, x1 = xB; xA = xC; xB = xD;
        xC = xp[4]; xD = xp[5];
        h = ftanh(XH(x0,0));                  // j=0 (h was 0)
        PSTEP(0, XH(x0,1), 1,0,0);            // j=1
        PSTEP(0, XH(x0,2), 1,1,0);            // j=2
        PSTEP(1, XH(x0,3), 1,1,1);            // j=3 -> act 1
        PSTEP(2, XH(x1,0), 1,1,1);            // j=4 -> act 2
        PSTEP(3, XH(x1,1), 1,1,1);            // j=5 -> act 3
        PSTEP(4, XH(x1,2), 1,1,1);            // j=6 -> act 4
        PSTEP(5, XH(x1,3), 1,1,1);            // j=7 -> act 5
    }
    __syncthreads();

    // ---- phase 1: producer group 1 (acts 6..13) || consumer acts 1..5 ----
    if (wid == 0) PGROUP(1);
    if (wid == 1) { CSTEP(1); CSTEP(2); CSTEP(3); CSTEP(4); CSTEP(5); }
    __syncthreads();

    // ---- phases 2..31: producer group G (acts 8G-2..8G+5) || consumer acts 8G-10..8G-3 ----
    #pragma unroll 1
    for (int G = 2; G <= 31; ++G) {
        if (wid == 0) PGROUP(G);
        if (wid == 1) {
            const int t0 = 8*G - 10;
            CSTEP(t0+0); CSTEP(t0+1); CSTEP(t0+2); CSTEP(t0+3);
            CSTEP(t0+4); CSTEP(t0+5); CSTEP(t0+6); CSTEP(t0+7);
        }
        __syncthreads();
    }

    // ---- drain: producer acts 254,255 || consumer acts 246..253 ----
    if (wid == 0) { PSTEP(254, 0.0f, 0,1,1); PSTEP(255, 0.0f, 0,0,1); }
    if (wid == 1) {
        CSTEP(246); CSTEP(247); CSTEP(248); CSTEP(249);
        CSTEP(250); CSTEP(251); CSTEP(252); CSTEP(253);
    }
    __syncthreads();
    if (wid == 1) { CSTEP(254); CSTEP(255); }

#undef CSTEP
#undef PGROUP
#undef PSTEP
#undef XH
}

extern "C" void kernel_launch(void* const* d_in, const int* in_sizes, int n_in,
                              void* d_out, int out_size, void* d_ws, size_t ws_size,
                              hipStream_t stream) {
    (void)in_sizes; (void)n_in; (void)ws_size; (void)out_size;
    __half* xws = (__half*)d_ws;   // 4096*16*256 fp16 = 33.5 MB
    xw_kernel<<<NB/4, 256, 0, stream>>>(
        (const float*)d_in[1],  // covariates_seq
        (const float*)d_in[2],  // ln_gamma
        (const float*)d_in[3],  // ln_beta
        (const float*)d_in[4],  // rnn_wx
        (const float*)d_in[6],  // rnn_b
        xws);
    scan_pc<<<NB/4, 128, 0, stream>>>(
        (const float*)d_in[0],  // states_seq
        xws,
        (const float*)d_in[5],  // rnn_wh
        (const float*)d_in[7],  // d1_w
        (const float*)d_in[8],  // d1_b
        (const float*)d_in[9],  // d2_w
        (const float*)d_in[10], // d2_b
        (float*)d_out);
}